// Round 1
// 1211.669 us; speedup vs baseline: 1.0107x; 1.0107x over previous
//
#include <hip/hip_runtime.h>

// SparseLinear: out[b,k] = dot(embed[b,:], sp_weight[shortlist[b,k],:]) + sp_bias[shortlist[b,k]]
// B=512, K=800, D=512, L=500000. fp32.
//
// v2: MLP-maximized gather. Per wave iteration: 8 k handled at once ->
// 16 independent 1KB coalesced loads in flight (vs 4 in v1), indices
// prefetched one iteration ahead (no loop-top scalar stall), 8 interleaved
// butterfly reduces, per-lane bias load + stores from lanes 0-7.

#define DDIM 512
#define KTOT 800
#define KCHUNKS 5
#define KPB (KTOT / KCHUNKS)   // 160 k per block
#define KITER 5                // 4 waves * 8 k * 5 iters = 160

__device__ __forceinline__ float dot8(const float4 a0, const float4 a1,
                                      const float4 e0, const float4 e1) {
    return a0.x * e0.x + a0.y * e0.y + a0.z * e0.z + a0.w * e0.w
         + a1.x * e1.x + a1.y * e1.y + a1.z * e1.z + a1.w * e1.w;
}

__global__ __launch_bounds__(256, 4)
void sparse_linear_kernel(const float* __restrict__ embed,
                          const int* __restrict__ shortlist,
                          const float* __restrict__ sp_weight,
                          const float* __restrict__ sp_bias,
                          float* __restrict__ out) {
    const int b     = blockIdx.x;
    const int kbase = blockIdx.y * KPB;
    const int wave  = (int)(threadIdx.x >> 6);
    const int lane  = (int)(threadIdx.x & 63);

    // Lane's 8 embed floats, reused across all k of this batch row.
    const float4* e4 = (const float4*)(embed + (size_t)b * DDIM);
    const float4 e0 = e4[lane];
    const float4 e1 = e4[64 + lane];

    const int* sl_row  = shortlist + (size_t)b * KTOT;
    float*     out_row = out + (size_t)b * KTOT;

    // Wave w covers k = kbase + 8w + 32i + j, j<8, i<5.  16B-aligned int4 loads.
    const int k0 = kbase + wave * 8;
    int4 ia = *(const int4*)(sl_row + k0);
    int4 ib = *(const int4*)(sl_row + k0 + 4);

    #pragma unroll 1
    for (int i = 0; i < KITER; ++i) {
        const int k = k0 + i * 32;

        // ---- issue all 16 row loads up front (16KB in flight per wave) ----
        const float4* w0 = (const float4*)(sp_weight + (size_t)ia.x * DDIM);
        const float4* w1 = (const float4*)(sp_weight + (size_t)ia.y * DDIM);
        const float4* w2 = (const float4*)(sp_weight + (size_t)ia.z * DDIM);
        const float4* w3 = (const float4*)(sp_weight + (size_t)ia.w * DDIM);
        const float4* w4 = (const float4*)(sp_weight + (size_t)ib.x * DDIM);
        const float4* w5 = (const float4*)(sp_weight + (size_t)ib.y * DDIM);
        const float4* w6 = (const float4*)(sp_weight + (size_t)ib.z * DDIM);
        const float4* w7 = (const float4*)(sp_weight + (size_t)ib.w * DDIM);

        const float4 a00 = w0[lane], a01 = w0[64 + lane];
        const float4 a10 = w1[lane], a11 = w1[64 + lane];
        const float4 a20 = w2[lane], a21 = w2[64 + lane];
        const float4 a30 = w3[lane], a31 = w3[64 + lane];
        const float4 a40 = w4[lane], a41 = w4[64 + lane];
        const float4 a50 = w5[lane], a51 = w5[64 + lane];
        const float4 a60 = w6[lane], a61 = w6[64 + lane];
        const float4 a70 = w7[lane], a71 = w7[64 + lane];

        // ---- per-lane bias gather (lanes 0-7), issued early to hide latency ----
        int myidx = ia.x;
        myidx = (lane == 1) ? ia.y : myidx;
        myidx = (lane == 2) ? ia.z : myidx;
        myidx = (lane == 3) ? ia.w : myidx;
        myidx = (lane == 4) ? ib.x : myidx;
        myidx = (lane == 5) ? ib.y : myidx;
        myidx = (lane == 6) ? ib.z : myidx;
        myidx = (lane == 7) ? ib.w : myidx;
        float mybias = 0.0f;
        if (lane < 8) mybias = sp_bias[myidx];

        // ---- prefetch next iteration's indices (kills loop-top stall) ----
        int4 na = ia, nb = ib;
        if (i < KITER - 1) {
            na = *(const int4*)(sl_row + k + 32);
            nb = *(const int4*)(sl_row + k + 36);
        }

        // ---- 8 partial dot products ----
        float p0 = dot8(a00, a01, e0, e1);
        float p1 = dot8(a10, a11, e0, e1);
        float p2 = dot8(a20, a21, e0, e1);
        float p3 = dot8(a30, a31, e0, e1);
        float p4 = dot8(a40, a41, e0, e1);
        float p5 = dot8(a50, a51, e0, e1);
        float p6 = dot8(a60, a61, e0, e1);
        float p7 = dot8(a70, a71, e0, e1);

        // ---- 8 interleaved butterfly reductions (sum in every lane) ----
        #pragma unroll
        for (int m = 1; m < 64; m <<= 1) {
            p0 += __shfl_xor(p0, m, 64);
            p1 += __shfl_xor(p1, m, 64);
            p2 += __shfl_xor(p2, m, 64);
            p3 += __shfl_xor(p3, m, 64);
            p4 += __shfl_xor(p4, m, 64);
            p5 += __shfl_xor(p5, m, 64);
            p6 += __shfl_xor(p6, m, 64);
            p7 += __shfl_xor(p7, m, 64);
        }

        // ---- lanes 0-7 each write one output (one coalesced 32B txn) ----
        if (lane < 8) {
            float myp = p0;
            myp = (lane == 1) ? p1 : myp;
            myp = (lane == 2) ? p2 : myp;
            myp = (lane == 3) ? p3 : myp;
            myp = (lane == 4) ? p4 : myp;
            myp = (lane == 5) ? p5 : myp;
            myp = (lane == 6) ? p6 : myp;
            myp = (lane == 7) ? p7 : myp;
            out_row[k + lane] = myp + mybias;
        }

        ia = na;
        ib = nb;
    }
}

extern "C" void kernel_launch(void* const* d_in, const int* in_sizes, int n_in,
                              void* d_out, int out_size, void* d_ws, size_t ws_size,
                              hipStream_t stream) {
    const float* embed     = (const float*)d_in[0];
    const int*   shortlist = (const int*)d_in[1];
    const float* sp_weight = (const float*)d_in[2];
    const float* sp_bias   = (const float*)d_in[3];
    float* out = (float*)d_out;

    dim3 grid(512, KCHUNKS);
    dim3 block(256);
    hipLaunchKernelGGL(sparse_linear_kernel, grid, block, 0, stream,
                       embed, shortlist, sp_weight, sp_bias, out);
}